// Round 17
// baseline (248.402 us; speedup 1.0000x reference)
//
#include <hip/hip_runtime.h>
#include <hip/hip_bf16.h>
#include <stdint.h>

#define NBAT 4
#define SEQ 1024
#define CH 1024
#define NH 16
#define DH 64
#define MTOT (NBAT*SEQ)   // 4096

typedef __attribute__((ext_vector_type(8))) short bf16x8;
typedef __attribute__((ext_vector_type(4))) float f32x4;
typedef unsigned short u16;

// Raw barrier is NOT a compiler fence: bracket it (R2 lesson).
#define FENCE() asm volatile("" ::: "memory")
#define BAR() do { FENCE(); __builtin_amdgcn_s_barrier(); FENCE(); } while (0)
#define WAIT_VM0() asm volatile("s_waitcnt vmcnt(0)" ::: "memory")
#define WAIT_VM8() asm volatile("s_waitcnt vmcnt(8)" ::: "memory")
#define WAIT_LGKM0() asm volatile("s_waitcnt lgkmcnt(0)" ::: "memory")

__device__ __forceinline__ void g2l16(void* lds, const void* g) {
  __builtin_amdgcn_global_load_lds(
      (const __attribute__((address_space(1))) uint32_t*)g,
      (__attribute__((address_space(3))) uint32_t*)lds, 16, 0, 0);
}

__device__ __forceinline__ u16 f2bf(float f) {   // RNE float->bf16
  union { float f; uint32_t u; } v; v.f = f;
  uint32_t lsb = (v.u >> 16) & 1u;
  v.u += 0x7fffu + lsb;
  return (u16)(v.u >> 16);
}

// swizzled bf16x8 fragment read from a [rows][64 u16] LDS tile (128 B rows)
__device__ __forceinline__ bf16x8 ldfrag(const u16* base, int row, int koff) {
  return *(const bf16x8*)((const char*)base + row * 128 + (koff ^ ((row & 7) << 4)));
}

// ---------------------------------------------------------------------------
// x fp32 -> bf16 (4M elems)
// ---------------------------------------------------------------------------
__global__ __launch_bounds__(256) void cvt_x(const float* __restrict__ x,
                                             u16* __restrict__ xb) {
  int i = blockIdx.x * 256 + threadIdx.x;
  float4 v = ((const float4*)x)[i];
  ushort4 o;
  o.x = f2bf(v.x); o.y = f2bf(v.y); o.z = f2bf(v.z); o.w = f2bf(v.w);
  ((ushort4*)xb)[i] = o;
}

// ---------------------------------------------------------------------------
// W fp32 [1024][1024] -> Wt bf16 [n][k] (transposed), 64x64 tiles
// ---------------------------------------------------------------------------
__global__ __launch_bounds__(256) void wt_bf16(const float* __restrict__ W,
                                               u16* __restrict__ Wt) {
  __shared__ u16 tile[64][65];
  const int bi = blockIdx.x;      // n-tile
  const int bj = blockIdx.y;      // k-tile
  const int t = threadIdx.x;
  const int c4 = (t & 15) * 4, rr = t >> 4;
#pragma unroll
  for (int p = 0; p < 4; p++) {
    int r = p * 16 + rr;          // k within tile
    float4 v = *(const float4*)(W + (size_t)(bj * 64 + r) * CH + bi * 64 + c4);
    tile[r][c4 + 0] = f2bf(v.x); tile[r][c4 + 1] = f2bf(v.y);
    tile[r][c4 + 2] = f2bf(v.z); tile[r][c4 + 3] = f2bf(v.w);
  }
  __syncthreads();
  const int n = t >> 2, ks = (t & 3) * 16;
  u16 tmp[16];
#pragma unroll
  for (int i = 0; i < 16; i++) tmp[i] = tile[ks + i][n];
#pragma unroll
  for (int s = 0; s < 4; s++) {
    ushort4 o; o.x = tmp[4*s]; o.y = tmp[4*s+1]; o.z = tmp[4*s+2]; o.w = tmp[4*s+3];
    *(ushort4*)(Wt + (size_t)(bi * 64 + n) * CH + bj * 64 + ks + 4 * s) = o;
  }
}

// ---------------------------------------------------------------------------
// bf16 MFMA GEMM body: C[4096][1024] = A[4096][1024] @ Bt^T + bias
// ---------------------------------------------------------------------------
template<int MODE>
__device__ __forceinline__ void gemm_body(
    u16* As, u16* Bs,
    const u16* __restrict__ A, const u16* __restrict__ Bt,
    const float* __restrict__ bias, void* __restrict__ outp,
    float scale, int bn0, int bm0, int t)
{
  const int wid = t >> 6, lane = t & 63;
  const int wr = wid >> 1, wc = wid & 1;
  const int cl = lane & 15, g = lane >> 4;

  f32x4 acc[4][4] = {};
  const u16* ga = A  + (size_t)(bm0 + (t >> 2)) * CH + (t & 3) * 8;
  const u16* gb = Bt + (size_t)(bn0 + (t >> 2)) * CH + (t & 3) * 8;

  for (int k0 = 0; k0 < CH; k0 += 32) {
    g2l16(As + t * 8,        ga + k0);
    g2l16(As + 2048 + t * 8, ga + (size_t)64 * CH + k0);
    g2l16(Bs + t * 8,        gb + k0);
    g2l16(Bs + 2048 + t * 8, gb + (size_t)64 * CH + k0);
    __syncthreads();
    bf16x8 af[4], bfr[4];
#pragma unroll
    for (int f = 0; f < 4; f++) {
      af[f]  = *(const bf16x8*)(As + (wr * 64 + f * 16 + cl) * 32 + g * 8);
      bfr[f] = *(const bf16x8*)(Bs + (wc * 64 + f * 16 + cl) * 32 + g * 8);
    }
#pragma unroll
    for (int i = 0; i < 4; i++)
#pragma unroll
      for (int j = 0; j < 4; j++)
        acc[i][j] = __builtin_amdgcn_mfma_f32_16x16x32_bf16(af[i], bfr[j], acc[i][j], 0, 0, 0);
    __syncthreads();
  }

#pragma unroll
  for (int i = 0; i < 4; i++)
#pragma unroll
    for (int j = 0; j < 4; j++) {
      const int row0 = bm0 + wr * 64 + i * 16 + g * 4;
      const int col  = bn0 + wc * 64 + j * 16 + cl;
      const float bb = bias[col];
      f32x4 v = acc[i][j];
      if (MODE == 0) {
        u16* o = (u16*)outp;
#pragma unroll
        for (int q = 0; q < 4; q++) o[(size_t)(row0 + q) * CH + col] = f2bf((v[q] + bb) * scale);
      } else if (MODE == 1) {
        u16* o = (u16*)outp;
        ushort4 pk;
        pk.x = f2bf(v[0] + bb); pk.y = f2bf(v[1] + bb);
        pk.z = f2bf(v[2] + bb); pk.w = f2bf(v[3] + bb);
        *(ushort4*)(o + (size_t)col * MTOT + row0) = pk;
      } else {
        float* o = (float*)outp;
#pragma unroll
        for (int q = 0; q < 4; q++) o[(size_t)(row0 + q) * CH + col] = v[q] + bb;
      }
    }
}

// Q/K/V in one launch: grid.z selects target
__global__ __launch_bounds__(256) void gemm_qkv(
    const u16* __restrict__ A,
    const u16* __restrict__ Wtq, const float* __restrict__ bq, u16* __restrict__ qo,
    const u16* __restrict__ Wtk, const float* __restrict__ bk, u16* __restrict__ ko,
    const u16* __restrict__ Wtv, const float* __restrict__ bv, u16* __restrict__ vo)
{
  __shared__ u16 As[128 * 32];
  __shared__ u16 Bs[128 * 32];
  const int t = threadIdx.x;
  const int bn0 = blockIdx.x * 128, bm0 = blockIdx.y * 128;
  if (blockIdx.z == 0)
    gemm_body<0>(As, Bs, A, Wtq, bq, qo, 0.0625f, bn0, bm0, t);   // pre-scaled Q
  else if (blockIdx.z == 1)
    gemm_body<0>(As, Bs, A, Wtk, bk, ko, 1.0f, bn0, bm0, t);
  else
    gemm_body<1>(As, Bs, A, Wtv, bv, vo, 1.0f, bn0, bm0, t);
}

__global__ __launch_bounds__(256) void gemm_out(
    const u16* __restrict__ A, const u16* __restrict__ Bt,
    const float* __restrict__ bias, float* __restrict__ outp)
{
  __shared__ u16 As[128 * 32];
  __shared__ u16 Bs[128 * 32];
  gemm_body<2>(As, Bs, A, Bt, bias, outp, 1.0f, blockIdx.x * 128, blockIdx.y * 128,
               threadIdx.x);
}

// ---------------------------------------------------------------------------
// Fused scores -> entmax(1.5, Newton) -> PV.
// R17: R12 schedule with 512 thr / 32 Q-rows per block (2048 blocks).
// Same 128-row chunks (8 score + 8 PV iters), but 8 waves SHARE each staged
// chunk: staged K/V bytes, g2l16 count (one call = full 64-row sub-tile at
// 512 thr), barrier events, and L2 traffic all halve per Q-row.  LDS 40 KB
// (2x16 KB buf + 2x4 KB pcb) -> 4 blocks/CU = 2048 thr (full).  vmcnt by
// queue simulation: scores VM0; PV VM0/VM8 (V(vc)'s 2 ops oldest, 8 stores
// float).  Scalar Newton 7 iters, NT attn stores -- all verified pieces.
// ---------------------------------------------------------------------------
__global__ __launch_bounds__(512, 4) void fused_attn(
    const u16* __restrict__ q, const u16* __restrict__ k,
    const u16* __restrict__ vt, float* __restrict__ attn,
    u16* __restrict__ o)
{
  __shared__ u16 buf[2][128 * 64];   // 2 x 16 KB (each: two 64x64 sub-tiles)
  __shared__ u16 pcb[2][8 * 256];    // 2 x 4 KB, per-sub per-wave P bounce

  const int t = threadIdx.x;
  const int w = t >> 6, lane = t & 63;
  const int cl = lane & 15, g = lane >> 4;

  // XCD-clustered decode: lin%8 fixes bh%8 => per-XCD K/V set = 2 MB (L2-fit)
  const int lin = blockIdx.x;                 // 0..2047
  const int u = lin >> 3;                     // 0..255
  const int n0 = (u & 31) * 32;               // 32-row Q tile
  const int bh = (lin & 7) | ((u >> 5) << 3); // 0..63
  const int b = bh >> 4, h = bh & 15;
  const int r0 = w * 4;                       // wave's 4 Q-rows within tile

  const u16* qb = q  + ((size_t)(b * SEQ + n0) * CH + h * DH);
  const u16* kb = k  + ((size_t)(b * SEQ) * CH + h * DH);
  const u16* vb = vt + ((size_t)(h * DH) * MTOT + b * SEQ);

  // Replicated Q A-fragments (rows r0..r0+3 repeated): row cl -> r0+(cl&3)
  const bf16x8 aq0 = *(const bf16x8*)(qb + (size_t)(r0 + (cl & 3)) * CH + g * 8);
  const bf16x8 aq1 = *(const bf16x8*)(qb + (size_t)(r0 + (cl & 3)) * CH + 32 + g * 8);

  // staging geometry: 512 thr x 16 B = 8 KB per call = one 64-row sub-tile
  const int srow = t >> 3;                                    // 0..63
  const int sbyte = ((t & 7) * 16) ^ ((srow & 7) << 4);       // inv-swz src
  const int scol = sbyte >> 1;                                // u16 units

  // prologue: stage K chunk 0 (rows 0..127) -- 2 calls
  {
    u16* d = buf[0];
    g2l16(d + t * 8,        kb + (size_t)srow * CH + scol);
    g2l16(d + 4096 + t * 8, kb + (size_t)(srow + 64) * CH + scol);
  }

  float xa[4][16];

  // ---- scores: 8 chunks of 128 K-rows ----
#pragma unroll
  for (int c = 0; c < 8; ++c) {
    WAIT_LGKM0();                        // my ds reads of other buf complete
    WAIT_VM0();                          // chunk c staging (2 ops) done
    BAR();
    if (c < 7) {
      const u16* kc = kb + (size_t)(128 * (c + 1)) * CH;
      u16* d = buf[(c + 1) & 1];
      g2l16(d + t * 8,        kc + (size_t)srow * CH + scol);
      g2l16(d + 4096 + t * 8, kc + (size_t)(srow + 64) * CH + scol);
    }
#pragma unroll
    for (int s = 0; s < 2; ++s) {        // two 64-row sub-tiles
      const u16* kc = buf[c & 1] + s * 4096;
      f32x4 sc0 = {}, sc1 = {}, sc2 = {}, sc3 = {};
      sc0 = __builtin_amdgcn_mfma_f32_16x16x32_bf16(aq0, ldfrag(kc, cl,      g * 16), sc0, 0, 0, 0);
      sc0 = __builtin_amdgcn_mfma_f32_16x16x32_bf16(aq1, ldfrag(kc, cl,      64 + g * 16), sc0, 0, 0, 0);
      sc1 = __builtin_amdgcn_mfma_f32_16x16x32_bf16(aq0, ldfrag(kc, 16 + cl, g * 16), sc1, 0, 0, 0);
      sc1 = __builtin_amdgcn_mfma_f32_16x16x32_bf16(aq1, ldfrag(kc, 16 + cl, 64 + g * 16), sc1, 0, 0, 0);
      sc2 = __builtin_amdgcn_mfma_f32_16x16x32_bf16(aq0, ldfrag(kc, 32 + cl, g * 16), sc2, 0, 0, 0);
      sc2 = __builtin_amdgcn_mfma_f32_16x16x32_bf16(aq1, ldfrag(kc, 32 + cl, 64 + g * 16), sc2, 0, 0, 0);
      sc3 = __builtin_amdgcn_mfma_f32_16x16x32_bf16(aq0, ldfrag(kc, 48 + cl, g * 16), sc3, 0, 0, 0);
      sc3 = __builtin_amdgcn_mfma_f32_16x16x32_bf16(aq1, ldfrag(kc, 48 + cl, 64 + g * 16), sc3, 0, 0, 0);
#pragma unroll
      for (int qq = 0; qq < 4; ++qq) {   // keep row-tile == g
        float v = sc0[qq];
        v = (g == 1) ? sc1[qq] : v;
        v = (g == 2) ? sc2[qq] : v;
        v = (g == 3) ? sc3[qq] : v;
        xa[qq][2 * c + s] = v;           // Q pre-scaled: already *(1/8)*(a-1)
      }
    }
  }

  // stage V chunk 0 (V^T: 64 dh rows x m 0..127); latency hides under Newton
  {
    u16* d = buf[0];
    g2l16(d + t * 8,        vb + (size_t)srow * MTOT + scol);
    g2l16(d + 4096 + t * 8, vb + (size_t)srow * MTOT + 64 + scol);
  }

  // ---- entmax tau via Newton (alpha=1.5), SCALAR, 4 rows/wave ----
  float tau[4];
#pragma unroll
  for (int r = 0; r < 4; ++r) {
    float m = xa[r][0];
#pragma unroll
    for (int j = 1; j < 16; ++j) m = fmaxf(m, xa[r][j]);
#pragma unroll
    for (int off = 1; off < 64; off <<= 1) m = fmaxf(m, __shfl_xor(m, off));
    tau[r] = m - 1.0f;
  }
  for (int it = 0; it < 7; ++it) {       // 7 iters: verified converged (R7/R11)
    float ss[4], sd[4];
#pragma unroll
    for (int r = 0; r < 4; ++r) {
      float s2 = 0.f, s1 = 0.f;
#pragma unroll
      for (int j = 0; j < 16; ++j) {
        float d = fmaxf(xa[r][j] - tau[r], 0.f);
        s2 = fmaf(d, d, s2); s1 += d;
      }
      ss[r] = s2; sd[r] = s1;
    }
#pragma unroll
    for (int off = 1; off < 64; off <<= 1) {
#pragma unroll
      for (int r = 0; r < 4; ++r) {
        ss[r] += __shfl_xor(ss[r], off);
        sd[r] += __shfl_xor(sd[r], off);
      }
    }
#pragma unroll
    for (int r = 0; r < 4; ++r)
      tau[r] += (ss[r] - 1.0f) / (sd[r] + sd[r]);
  }
  float inv[4];
#pragma unroll
  for (int r = 0; r < 4; ++r) {
    float s2 = 0.f;
#pragma unroll
    for (int j = 0; j < 16; ++j) { float d = fmaxf(xa[r][j] - tau[r], 0.f); s2 = fmaf(d, d, s2); }
#pragma unroll
    for (int off = 1; off < 64; off <<= 1) s2 += __shfl_xor(s2, off);
    inv[r] = 1.0f / s2;
  }

  // ---- PV: 8 chunks of 128 V-rows ----
  f32x4 pva0 = {}, pva1 = {}, pva2 = {}, pva3 = {};
  float* ab = attn + (size_t)bh * SEQ * SEQ + (size_t)(n0 + r0) * SEQ;
#pragma unroll
  for (int vc = 0; vc < 8; ++vc) {
    float pval[2][4];
#pragma unroll
    for (int s = 0; s < 2; ++s) {
      char* pw = (char*)pcb[s] + w * 512;
#pragma unroll
      for (int r = 0; r < 4; ++r) {
        float d = fmaxf(xa[r][2 * vc + s] - tau[r], 0.f);
        pval[s][r] = d * d * inv[r];
        *(u16*)(pw + r * 128 + ((lane * 2) ^ (r << 4))) = f2bf(pval[s][r]);
      }
    }
    WAIT_LGKM0();                        // pcb writes + prev ds reads done
    if (vc == 0) { WAIT_VM0(); } else { WAIT_VM8(); }  // pf(vc) done; prev stores float
    BAR();
    if (vc < 7) {
      const u16* vc2 = vb + (size_t)128 * (vc + 1);
      u16* d = buf[(vc + 1) & 1];
      g2l16(d + t * 8,        vc2 + (size_t)srow * MTOT + scol);
      g2l16(d + 4096 + t * 8, vc2 + (size_t)srow * MTOT + 64 + scol);
    }
#pragma unroll
    for (int s = 0; s < 2; ++s) {
      const u16* vbu = buf[vc & 1] + s * 4096;
      const char* pw = (const char*)pcb[s] + w * 512;
      const bf16x8 ap0 = *(const bf16x8*)(pw + (cl & 3) * 128 + ((g * 16) ^ ((cl & 3) << 4)));
      const bf16x8 ap1 = *(const bf16x8*)(pw + (cl & 3) * 128 + ((64 + g * 16) ^ ((cl & 3) << 4)));
      pva0 = __builtin_amdgcn_mfma_f32_16x16x32_bf16(ap0, ldfrag(vbu, cl,      g * 16), pva0, 0, 0, 0);
      pva0 = __builtin_amdgcn_mfma_f32_16x16x32_bf16(ap1, ldfrag(vbu, cl,      64 + g * 16), pva0, 0, 0, 0);
      pva1 = __builtin_amdgcn_mfma_f32_16x16x32_bf16(ap0, ldfrag(vbu, 16 + cl, g * 16), pva1, 0, 0, 0);
      pva1 = __builtin_amdgcn_mfma_f32_16x16x32_bf16(ap1, ldfrag(vbu, 16 + cl, 64 + g * 16), pva1, 0, 0, 0);
      pva2 = __builtin_amdgcn_mfma_f32_16x16x32_bf16(ap0, ldfrag(vbu, 32 + cl, g * 16), pva2, 0, 0, 0);
      pva2 = __builtin_amdgcn_mfma_f32_16x16x32_bf16(ap1, ldfrag(vbu, 32 + cl, 64 + g * 16), pva2, 0, 0, 0);
      pva3 = __builtin_amdgcn_mfma_f32_16x16x32_bf16(ap0, ldfrag(vbu, 48 + cl, g * 16), pva3, 0, 0, 0);
      pva3 = __builtin_amdgcn_mfma_f32_16x16x32_bf16(ap1, ldfrag(vbu, 48 + cl, 64 + g * 16), pva3, 0, 0, 0);
    }
#pragma unroll
    for (int s = 0; s < 2; ++s)
#pragma unroll
      for (int r = 0; r < 4; ++r)
        __builtin_nontemporal_store(pval[s][r],
            ab + (size_t)r * SEQ + (2 * vc + s) * 64 + lane);
  }

  // output: lane stores dh-subtile == g  => column = h*DH + lane
  u16* ob = o + (size_t)(b * SEQ + n0 + r0) * CH + h * DH + lane;
#pragma unroll
  for (int qq = 0; qq < 4; ++qq) {
    float v = pva0[qq];
    v = (g == 1) ? pva1[qq] : v;
    v = (g == 2) ? pva2[qq] : v;
    v = (g == 3) ? pva3[qq] : v;
    ob[(size_t)qq * CH] = f2bf(v);
  }
}

// ---------------------------------------------------------------------------
extern "C" void kernel_launch(void* const* d_in, const int* in_sizes, int n_in,
                              void* d_out, int out_size, void* d_ws, size_t ws_size,
                              hipStream_t stream)
{
  const float* x  = (const float*)d_in[0];
  const float* Wq = (const float*)d_in[1];
  const float* bq = (const float*)d_in[2];
  const float* Wk = (const float*)d_in[3];
  const float* bk = (const float*)d_in[4];
  const float* Wv = (const float*)d_in[5];
  const float* bv = (const float*)d_in[6];
  const float* Wo = (const float*)d_in[7];
  const float* bo = (const float*)d_in[8];

  float* out0 = (float*)d_out;                        // [B,SEQ,CH] fp32
  float* attn = out0 + (size_t)NBAT * SEQ * CH;       // [B,H,SEQ,SEQ] fp32

  const size_t T = (size_t)MTOT * CH;                 // 4M elems
  u16* xb  = (u16*)d_ws;
  u16* qw  = xb  + T;
  u16* kw  = qw  + T;
  u16* vtw = kw  + T;
  u16* ow  = vtw + T;
  u16* wtq = ow  + T;
  u16* wtk = wtq + (size_t)CH * CH;
  u16* wtv = wtk + (size_t)CH * CH;
  u16* wto = wtv + (size_t)CH * CH;

  cvt_x<<<T / (4 * 256), 256, 0, stream>>>(x, xb);
  wt_bf16<<<dim3(16, 16), 256, 0, stream>>>(Wq, wtq);
  wt_bf16<<<dim3(16, 16), 256, 0, stream>>>(Wk, wtk);
  wt_bf16<<<dim3(16, 16), 256, 0, stream>>>(Wv, wtv);
  wt_bf16<<<dim3(16, 16), 256, 0, stream>>>(Wo, wto);

  gemm_qkv<<<dim3(CH / 128, MTOT / 128, 3), 256, 0, stream>>>(
      xb, wtq, bq, qw, wtk, bk, kw, wtv, bv, vtw);

  fused_attn<<<2048, 512, 0, stream>>>(qw, kw, vtw, attn, ow);

  gemm_out<<<dim3(CH / 128, MTOT / 128), 256, 0, stream>>>(ow, wto, bo, out0);
}

// Round 18
// 245.626 us; speedup vs baseline: 1.0113x; 1.0113x over previous
//
#include <hip/hip_runtime.h>
#include <hip/hip_bf16.h>
#include <stdint.h>

#define NBAT 4
#define SEQ 1024
#define CH 1024
#define NH 16
#define DH 64
#define MTOT (NBAT*SEQ)   // 4096

typedef __attribute__((ext_vector_type(8))) short bf16x8;
typedef __attribute__((ext_vector_type(4))) float f32x4;
typedef unsigned short u16;

// Raw barrier is NOT a compiler fence: bracket it (R2 lesson).
#define FENCE() asm volatile("" ::: "memory")
#define BAR() do { FENCE(); __builtin_amdgcn_s_barrier(); FENCE(); } while (0)
#define WAIT_VM0() asm volatile("s_waitcnt vmcnt(0)" ::: "memory")
#define WAIT_VM8() asm volatile("s_waitcnt vmcnt(8)" ::: "memory")
#define WAIT_LGKM0() asm volatile("s_waitcnt lgkmcnt(0)" ::: "memory")

__device__ __forceinline__ void g2l16(void* lds, const void* g) {
  __builtin_amdgcn_global_load_lds(
      (const __attribute__((address_space(1))) uint32_t*)g,
      (__attribute__((address_space(3))) uint32_t*)lds, 16, 0, 0);
}

__device__ __forceinline__ u16 f2bf(float f) {   // RNE float->bf16
  union { float f; uint32_t u; } v; v.f = f;
  uint32_t lsb = (v.u >> 16) & 1u;
  v.u += 0x7fffu + lsb;
  return (u16)(v.u >> 16);
}

// swizzled bf16x8 fragment read from a [rows][64 u16] LDS tile (128 B rows)
__device__ __forceinline__ bf16x8 ldfrag(const u16* base, int row, int koff) {
  return *(const bf16x8*)((const char*)base + row * 128 + (koff ^ ((row & 7) << 4)));
}

// ---------------------------------------------------------------------------
// x fp32 -> bf16 (4M elems)
// ---------------------------------------------------------------------------
__global__ __launch_bounds__(256) void cvt_x(const float* __restrict__ x,
                                             u16* __restrict__ xb) {
  int i = blockIdx.x * 256 + threadIdx.x;
  float4 v = ((const float4*)x)[i];
  ushort4 o;
  o.x = f2bf(v.x); o.y = f2bf(v.y); o.z = f2bf(v.z); o.w = f2bf(v.w);
  ((ushort4*)xb)[i] = o;
}

// ---------------------------------------------------------------------------
// W fp32 [1024][1024] -> Wt bf16 [n][k] (transposed), 64x64 tiles
// ---------------------------------------------------------------------------
__global__ __launch_bounds__(256) void wt_bf16(const float* __restrict__ W,
                                               u16* __restrict__ Wt) {
  __shared__ u16 tile[64][65];
  const int bi = blockIdx.x;      // n-tile
  const int bj = blockIdx.y;      // k-tile
  const int t = threadIdx.x;
  const int c4 = (t & 15) * 4, rr = t >> 4;
#pragma unroll
  for (int p = 0; p < 4; p++) {
    int r = p * 16 + rr;          // k within tile
    float4 v = *(const float4*)(W + (size_t)(bj * 64 + r) * CH + bi * 64 + c4);
    tile[r][c4 + 0] = f2bf(v.x); tile[r][c4 + 1] = f2bf(v.y);
    tile[r][c4 + 2] = f2bf(v.z); tile[r][c4 + 3] = f2bf(v.w);
  }
  __syncthreads();
  const int n = t >> 2, ks = (t & 3) * 16;
  u16 tmp[16];
#pragma unroll
  for (int i = 0; i < 16; i++) tmp[i] = tile[ks + i][n];
#pragma unroll
  for (int s = 0; s < 4; s++) {
    ushort4 o; o.x = tmp[4*s]; o.y = tmp[4*s+1]; o.z = tmp[4*s+2]; o.w = tmp[4*s+3];
    *(ushort4*)(Wt + (size_t)(bi * 64 + n) * CH + bj * 64 + ks + 4 * s) = o;
  }
}

// ---------------------------------------------------------------------------
// bf16 MFMA GEMM body: C[4096][1024] = A[4096][1024] @ Bt^T + bias
// ---------------------------------------------------------------------------
template<int MODE>
__device__ __forceinline__ void gemm_body(
    u16* As, u16* Bs,
    const u16* __restrict__ A, const u16* __restrict__ Bt,
    const float* __restrict__ bias, void* __restrict__ outp,
    float scale, int bn0, int bm0, int t)
{
  const int wid = t >> 6, lane = t & 63;
  const int wr = wid >> 1, wc = wid & 1;
  const int cl = lane & 15, g = lane >> 4;

  f32x4 acc[4][4] = {};
  const u16* ga = A  + (size_t)(bm0 + (t >> 2)) * CH + (t & 3) * 8;
  const u16* gb = Bt + (size_t)(bn0 + (t >> 2)) * CH + (t & 3) * 8;

  for (int k0 = 0; k0 < CH; k0 += 32) {
    g2l16(As + t * 8,        ga + k0);
    g2l16(As + 2048 + t * 8, ga + (size_t)64 * CH + k0);
    g2l16(Bs + t * 8,        gb + k0);
    g2l16(Bs + 2048 + t * 8, gb + (size_t)64 * CH + k0);
    __syncthreads();
    bf16x8 af[4], bfr[4];
#pragma unroll
    for (int f = 0; f < 4; f++) {
      af[f]  = *(const bf16x8*)(As + (wr * 64 + f * 16 + cl) * 32 + g * 8);
      bfr[f] = *(const bf16x8*)(Bs + (wc * 64 + f * 16 + cl) * 32 + g * 8);
    }
#pragma unroll
    for (int i = 0; i < 4; i++)
#pragma unroll
      for (int j = 0; j < 4; j++)
        acc[i][j] = __builtin_amdgcn_mfma_f32_16x16x32_bf16(af[i], bfr[j], acc[i][j], 0, 0, 0);
    __syncthreads();
  }

#pragma unroll
  for (int i = 0; i < 4; i++)
#pragma unroll
    for (int j = 0; j < 4; j++) {
      const int row0 = bm0 + wr * 64 + i * 16 + g * 4;
      const int col  = bn0 + wc * 64 + j * 16 + cl;
      const float bb = bias[col];
      f32x4 v = acc[i][j];
      if (MODE == 0) {
        u16* o = (u16*)outp;
#pragma unroll
        for (int q = 0; q < 4; q++) o[(size_t)(row0 + q) * CH + col] = f2bf((v[q] + bb) * scale);
      } else if (MODE == 1) {
        u16* o = (u16*)outp;
        ushort4 pk;
        pk.x = f2bf(v[0] + bb); pk.y = f2bf(v[1] + bb);
        pk.z = f2bf(v[2] + bb); pk.w = f2bf(v[3] + bb);
        *(ushort4*)(o + (size_t)col * MTOT + row0) = pk;
      } else {
        float* o = (float*)outp;
#pragma unroll
        for (int q = 0; q < 4; q++) o[(size_t)(row0 + q) * CH + col] = v[q] + bb;
      }
    }
}

// Q/K/V in one launch: grid.z selects target
__global__ __launch_bounds__(256) void gemm_qkv(
    const u16* __restrict__ A,
    const u16* __restrict__ Wtq, const float* __restrict__ bq, u16* __restrict__ qo,
    const u16* __restrict__ Wtk, const float* __restrict__ bk, u16* __restrict__ ko,
    const u16* __restrict__ Wtv, const float* __restrict__ bv, u16* __restrict__ vo)
{
  __shared__ u16 As[128 * 32];
  __shared__ u16 Bs[128 * 32];
  const int t = threadIdx.x;
  const int bn0 = blockIdx.x * 128, bm0 = blockIdx.y * 128;
  if (blockIdx.z == 0)
    gemm_body<0>(As, Bs, A, Wtq, bq, qo, 0.0625f, bn0, bm0, t);   // pre-scaled Q
  else if (blockIdx.z == 1)
    gemm_body<0>(As, Bs, A, Wtk, bk, ko, 1.0f, bn0, bm0, t);
  else
    gemm_body<1>(As, Bs, A, Wtv, bv, vo, 1.0f, bn0, bm0, t);
}

__global__ __launch_bounds__(256) void gemm_out(
    const u16* __restrict__ A, const u16* __restrict__ Bt,
    const float* __restrict__ bias, float* __restrict__ outp)
{
  __shared__ u16 As[128 * 32];
  __shared__ u16 Bs[128 * 32];
  gemm_body<2>(As, Bs, A, Bt, bias, outp, 1.0f, blockIdx.x * 128, blockIdx.y * 128,
               threadIdx.x);
}

// ---------------------------------------------------------------------------
// Fused scores -> entmax(1.5, Newton) -> PV.
// FINAL (R12/R16, best verified: 245.3 us total, absmax 0.004882812,
// reproduced twice).  128-row chunks (8 score + 8 PV iters); chunk = two
// 8 KB sub-tiles (64 rows x 128 B, XOR-swizzled), double-buffered 16 KB
// buffers (LDS 36 KB -> 4 blocks/CU).  Depth-1 prefetch; waits by queue
// simulation: scores vmcnt(0), PV vmcnt(8).  Scalar xa[4][16] + scalar
// Newton 7 iters (packed-f32x2 variant miscompiles: R8-R10).  NT attn
// stores.  Rejected by measurement: wave-autonomous/zero-barrier (R13-R15,
// TLP loss > barrier win), 512-thr staging amortization (R17, null).
// ---------------------------------------------------------------------------
__global__ __launch_bounds__(256, 4) void fused_attn(
    const u16* __restrict__ q, const u16* __restrict__ k,
    const u16* __restrict__ vt, float* __restrict__ attn,
    u16* __restrict__ o)
{
  __shared__ u16 buf[2][128 * 64];   // 2 x 16 KB (each: two 64x64 sub-tiles)
  __shared__ u16 pcb[2][4 * 256];    // 2 x 2 KB, per-sub per-wave P bounce

  const int t = threadIdx.x;
  const int w = t >> 6, lane = t & 63;
  const int cl = lane & 15, g = lane >> 4;

  // XCD-clustered decode: lin%8 fixes bh%8 => per-XCD K/V set L2-resident
  const int lin = blockIdx.x;
  const int u = lin >> 3;
  const int n0 = (u & 63) * 16;
  const int bh = (lin & 7) | ((u >> 6) << 3);
  const int b = bh >> 4, h = bh & 15;
  const int r0 = w * 4;

  const u16* qb = q  + ((size_t)(b * SEQ + n0) * CH + h * DH);
  const u16* kb = k  + ((size_t)(b * SEQ) * CH + h * DH);
  const u16* vb = vt + ((size_t)(h * DH) * MTOT + b * SEQ);

  // Replicated Q A-fragments (rows r0..r0+3 repeated): row cl -> r0+(cl&3)
  const bf16x8 aq0 = *(const bf16x8*)(qb + (size_t)(r0 + (cl & 3)) * CH + g * 8);
  const bf16x8 aq1 = *(const bf16x8*)(qb + (size_t)(r0 + (cl & 3)) * CH + 32 + g * 8);

  // staging geometry: 256 thr x 16 B = 4 KB per call -> 4 calls per 16 KB chunk
  const int srow = t >> 3;                                    // 0..31
  const int sbyte = ((t & 7) * 16) ^ ((srow & 7) << 4);       // inv-swz src
  const int scol = sbyte >> 1;                                // u16 units

  // prologue: stage K chunk 0 (rows 0..127)
  {
    u16* d = buf[0];
    g2l16(d + t * 8,        kb + (size_t)srow * CH + scol);
    g2l16(d + 2048 + t * 8, kb + (size_t)(srow + 32) * CH + scol);
    g2l16(d + 4096 + t * 8, kb + (size_t)(srow + 64) * CH + scol);
    g2l16(d + 6144 + t * 8, kb + (size_t)(srow + 96) * CH + scol);
  }

  float xa[4][16];

  // ---- scores: 8 chunks of 128 K-rows ----
#pragma unroll
  for (int c = 0; c < 8; ++c) {
    WAIT_LGKM0();                        // my ds reads of other buf complete
    WAIT_VM0();                          // chunk c staging (exactly 4 ops) done
    BAR();
    if (c < 7) {
      const u16* kc = kb + (size_t)(128 * (c + 1)) * CH;
      u16* d = buf[(c + 1) & 1];
      g2l16(d + t * 8,        kc + (size_t)srow * CH + scol);
      g2l16(d + 2048 + t * 8, kc + (size_t)(srow + 32) * CH + scol);
      g2l16(d + 4096 + t * 8, kc + (size_t)(srow + 64) * CH + scol);
      g2l16(d + 6144 + t * 8, kc + (size_t)(srow + 96) * CH + scol);
    }
#pragma unroll
    for (int s = 0; s < 2; ++s) {        // two 64-row sub-tiles
      const u16* kc = buf[c & 1] + s * 4096;
      f32x4 sc0 = {}, sc1 = {}, sc2 = {}, sc3 = {};
      sc0 = __builtin_amdgcn_mfma_f32_16x16x32_bf16(aq0, ldfrag(kc, cl,      g * 16), sc0, 0, 0, 0);
      sc0 = __builtin_amdgcn_mfma_f32_16x16x32_bf16(aq1, ldfrag(kc, cl,      64 + g * 16), sc0, 0, 0, 0);
      sc1 = __builtin_amdgcn_mfma_f32_16x16x32_bf16(aq0, ldfrag(kc, 16 + cl, g * 16), sc1, 0, 0, 0);
      sc1 = __builtin_amdgcn_mfma_f32_16x16x32_bf16(aq1, ldfrag(kc, 16 + cl, 64 + g * 16), sc1, 0, 0, 0);
      sc2 = __builtin_amdgcn_mfma_f32_16x16x32_bf16(aq0, ldfrag(kc, 32 + cl, g * 16), sc2, 0, 0, 0);
      sc2 = __builtin_amdgcn_mfma_f32_16x16x32_bf16(aq1, ldfrag(kc, 32 + cl, 64 + g * 16), sc2, 0, 0, 0);
      sc3 = __builtin_amdgcn_mfma_f32_16x16x32_bf16(aq0, ldfrag(kc, 48 + cl, g * 16), sc3, 0, 0, 0);
      sc3 = __builtin_amdgcn_mfma_f32_16x16x32_bf16(aq1, ldfrag(kc, 48 + cl, 64 + g * 16), sc3, 0, 0, 0);
#pragma unroll
      for (int qq = 0; qq < 4; ++qq) {   // keep row-tile == g
        float v = sc0[qq];
        v = (g == 1) ? sc1[qq] : v;
        v = (g == 2) ? sc2[qq] : v;
        v = (g == 3) ? sc3[qq] : v;
        xa[qq][2 * c + s] = v;           // Q pre-scaled: already *(1/8)*(a-1)
      }
    }
  }

  // stage V chunk 0 (V^T: 64 dh rows x m 0..127); latency hides under Newton
  {
    u16* d = buf[0];
    g2l16(d + t * 8,        vb + (size_t)srow * MTOT + scol);
    g2l16(d + 2048 + t * 8, vb + (size_t)(srow + 32) * MTOT + scol);
    g2l16(d + 4096 + t * 8, vb + (size_t)srow * MTOT + 64 + scol);
    g2l16(d + 6144 + t * 8, vb + (size_t)(srow + 32) * MTOT + 64 + scol);
  }

  // ---- entmax tau via Newton (alpha=1.5), SCALAR, 4 rows/wave ----
  float tau[4];
#pragma unroll
  for (int r = 0; r < 4; ++r) {
    float m = xa[r][0];
#pragma unroll
    for (int j = 1; j < 16; ++j) m = fmaxf(m, xa[r][j]);
#pragma unroll
    for (int off = 1; off < 64; off <<= 1) m = fmaxf(m, __shfl_xor(m, off));
    tau[r] = m - 1.0f;
  }
  for (int it = 0; it < 7; ++it) {       // 7 iters: verified converged (R7/R11)
    float ss[4], sd[4];
#pragma unroll
    for (int r = 0; r < 4; ++r) {
      float s2 = 0.f, s1 = 0.f;
#pragma unroll
      for (int j = 0; j < 16; ++j) {
        float d = fmaxf(xa[r][j] - tau[r], 0.f);
        s2 = fmaf(d, d, s2); s1 += d;
      }
      ss[r] = s2; sd[r] = s1;
    }
#pragma unroll
    for (int off = 1; off < 64; off <<= 1) {
#pragma unroll
      for (int r = 0; r < 4; ++r) {
        ss[r] += __shfl_xor(ss[r], off);
        sd[r] += __shfl_xor(sd[r], off);
      }
    }
#pragma unroll
    for (int r = 0; r < 4; ++r)
      tau[r] += (ss[r] - 1.0f) / (sd[r] + sd[r]);
  }
  float inv[4];
#pragma unroll
  for (int r = 0; r < 4; ++r) {
    float s2 = 0.f;
#pragma unroll
    for (int j = 0; j < 16; ++j) { float d = fmaxf(xa[r][j] - tau[r], 0.f); s2 = fmaf(d, d, s2); }
#pragma unroll
    for (int off = 1; off < 64; off <<= 1) s2 += __shfl_xor(s2, off);
    inv[r] = 1.0f / s2;
  }

  // ---- PV: 8 chunks of 128 V-rows ----
  f32x4 pva0 = {}, pva1 = {}, pva2 = {}, pva3 = {};
  float* ab = attn + (size_t)bh * SEQ * SEQ + (size_t)(n0 + r0) * SEQ;
#pragma unroll
  for (int vc = 0; vc < 8; ++vc) {
    float pval[2][4];
#pragma unroll
    for (int s = 0; s < 2; ++s) {
      char* pw = (char*)pcb[s] + w * 512;
#pragma unroll
      for (int r = 0; r < 4; ++r) {
        float d = fmaxf(xa[r][2 * vc + s] - tau[r], 0.f);
        pval[s][r] = d * d * inv[r];
        *(u16*)(pw + r * 128 + ((lane * 2) ^ (r << 4))) = f2bf(pval[s][r]);
      }
    }
    WAIT_LGKM0();                        // pcb writes + prev ds reads done
    if (vc == 0) { WAIT_VM0(); } else { WAIT_VM8(); }  // pf(vc) done; prev stores float
    BAR();
    if (vc < 7) {
      const u16* vc2 = vb + (size_t)128 * (vc + 1);
      u16* d = buf[(vc + 1) & 1];
      g2l16(d + t * 8,        vc2 + (size_t)srow * MTOT + scol);
      g2l16(d + 2048 + t * 8, vc2 + (size_t)(srow + 32) * MTOT + scol);
      g2l16(d + 4096 + t * 8, vc2 + (size_t)srow * MTOT + 64 + scol);
      g2l16(d + 6144 + t * 8, vc2 + (size_t)(srow + 32) * MTOT + 64 + scol);
    }
#pragma unroll
    for (int s = 0; s < 2; ++s) {
      const u16* vbu = buf[vc & 1] + s * 4096;
      const char* pw = (const char*)pcb[s] + w * 512;
      const bf16x8 ap0 = *(const bf16x8*)(pw + (cl & 3) * 128 + ((g * 16) ^ ((cl & 3) << 4)));
      const bf16x8 ap1 = *(const bf16x8*)(pw + (cl & 3) * 128 + ((64 + g * 16) ^ ((cl & 3) << 4)));
      pva0 = __builtin_amdgcn_mfma_f32_16x16x32_bf16(ap0, ldfrag(vbu, cl,      g * 16), pva0, 0, 0, 0);
      pva0 = __builtin_amdgcn_mfma_f32_16x16x32_bf16(ap1, ldfrag(vbu, cl,      64 + g * 16), pva0, 0, 0, 0);
      pva1 = __builtin_amdgcn_mfma_f32_16x16x32_bf16(ap0, ldfrag(vbu, 16 + cl, g * 16), pva1, 0, 0, 0);
      pva1 = __builtin_amdgcn_mfma_f32_16x16x32_bf16(ap1, ldfrag(vbu, 16 + cl, 64 + g * 16), pva1, 0, 0, 0);
      pva2 = __builtin_amdgcn_mfma_f32_16x16x32_bf16(ap0, ldfrag(vbu, 32 + cl, g * 16), pva2, 0, 0, 0);
      pva2 = __builtin_amdgcn_mfma_f32_16x16x32_bf16(ap1, ldfrag(vbu, 32 + cl, 64 + g * 16), pva2, 0, 0, 0);
      pva3 = __builtin_amdgcn_mfma_f32_16x16x32_bf16(ap0, ldfrag(vbu, 48 + cl, g * 16), pva3, 0, 0, 0);
      pva3 = __builtin_amdgcn_mfma_f32_16x16x32_bf16(ap1, ldfrag(vbu, 48 + cl, 64 + g * 16), pva3, 0, 0, 0);
    }
#pragma unroll
    for (int s = 0; s < 2; ++s)
#pragma unroll
      for (int r = 0; r < 4; ++r)
        __builtin_nontemporal_store(pval[s][r],
            ab + (size_t)r * SEQ + (2 * vc + s) * 64 + lane);
  }

  // output: lane stores dh-subtile == g  => column = h*DH + lane
  u16* ob = o + (size_t)(b * SEQ + n0 + r0) * CH + h * DH + lane;
#pragma unroll
  for (int qq = 0; qq < 4; ++qq) {
    float v = pva0[qq];
    v = (g == 1) ? pva1[qq] : v;
    v = (g == 2) ? pva2[qq] : v;
    v = (g == 3) ? pva3[qq] : v;
    ob[(size_t)qq * CH] = f2bf(v);
  }
}

// ---------------------------------------------------------------------------
extern "C" void kernel_launch(void* const* d_in, const int* in_sizes, int n_in,
                              void* d_out, int out_size, void* d_ws, size_t ws_size,
                              hipStream_t stream)
{
  const float* x  = (const float*)d_in[0];
  const float* Wq = (const float*)d_in[1];
  const float* bq = (const float*)d_in[2];
  const float* Wk = (const float*)d_in[3];
  const float* bk = (const float*)d_in[4];
  const float* Wv = (const float*)d_in[5];
  const float* bv = (const float*)d_in[6];
  const float* Wo = (const float*)d_in[7];
  const float* bo = (const float*)d_in[8];

  float* out0 = (float*)d_out;                        // [B,SEQ,CH] fp32
  float* attn = out0 + (size_t)NBAT * SEQ * CH;       // [B,H,SEQ,SEQ] fp32

  const size_t T = (size_t)MTOT * CH;                 // 4M elems
  u16* xb  = (u16*)d_ws;
  u16* qw  = xb  + T;
  u16* kw  = qw  + T;
  u16* vtw = kw  + T;
  u16* ow  = vtw + T;
  u16* wtq = ow  + T;
  u16* wtk = wtq + (size_t)CH * CH;
  u16* wtv = wtk + (size_t)CH * CH;
  u16* wto = wtv + (size_t)CH * CH;

  cvt_x<<<T / (4 * 256), 256, 0, stream>>>(x, xb);
  wt_bf16<<<dim3(16, 16), 256, 0, stream>>>(Wq, wtq);
  wt_bf16<<<dim3(16, 16), 256, 0, stream>>>(Wk, wtk);
  wt_bf16<<<dim3(16, 16), 256, 0, stream>>>(Wv, wtv);
  wt_bf16<<<dim3(16, 16), 256, 0, stream>>>(Wo, wto);

  gemm_qkv<<<dim3(CH / 128, MTOT / 128, 3), 256, 0, stream>>>(
      xb, wtq, bq, qw, wtk, bk, kw, wtv, bv, vtw);

  fused_attn<<<4096, 256, 0, stream>>>(qw, kw, vtw, attn, ow);

  gemm_out<<<dim3(CH / 128, MTOT / 128), 256, 0, stream>>>(ow, wto, bo, out0);
}